// Round 13
// baseline (52.983 us; speedup 1.0000x reference)
//
#include <hip/hip_runtime.h>

#define NPTS  131072        // B*G
#define GPTS  32768         // G

typedef __attribute__((ext_vector_type(4)))  _Float16 half4v;
typedef __attribute__((ext_vector_type(8)))  _Float16 half8v;
typedef __attribute__((ext_vector_type(16))) float    f32x16;

// global -> LDS direct copy, 16B per lane (dest = uniform base + lane*16)
__device__ __forceinline__ void gl_lds16(const void* g, void* l) {
    __builtin_amdgcn_global_load_lds((__attribute__((address_space(1))) const void*)g,
                                     (__attribute__((address_space(3))) void*)l,
                                     16, 0, 0);
}

// ---- sigmoid emulating the reference f32 pipeline (bit-faithful) ----------
__device__ __forceinline__ float sigf(float x) {
    x = fminf(fmaxf(x, -9.21f), 9.21f);
    float t = (float)exp(-(double)x);
    return 1.0f / (1.0f + t);
}

// ---- fused front-end -------------------------------------------------------
// blocks [0,512):    sigmoid + per-block min + grid clear
// blocks [512,530):  W -> 32x32x16 f16 B-fragments
// blocks [530,2578): feats f32 -> f16 rows (+1 zero row)
__global__ __launch_bounds__(256) void k_front(const float* __restrict__ anchor,
                                               const float* __restrict__ W,
                                               const float* __restrict__ feats,
                                               float* __restrict__ s0a,
                                               float* __restrict__ s1a,
                                               float2* __restrict__ blockmin,
                                               _Float16* __restrict__ bpk,
                                               _Float16* __restrict__ fb,
                                               int* __restrict__ grd) {
    const int bid = blockIdx.x;
    if (bid < 512) {
        __shared__ float red[8];
        int i = bid * 256 + threadIdx.x;            // [0,131072)
        int2 mone = {-1, -1};
        ((int2*)grd)[i] = mone;                     // clear 1 MB rulebook grid
        float2 a = ((const float2*)anchor)[i];
        float s0 = sigf(a.x);
        float s1 = sigf(a.y);
        s0a[i] = s0;
        s1a[i] = s1;
        float m0 = s0, m1 = s1;
        #pragma unroll
        for (int off = 32; off; off >>= 1) {
            m0 = fminf(m0, __shfl_down(m0, off));
            m1 = fminf(m1, __shfl_down(m1, off));
        }
        int wv = threadIdx.x >> 6;
        if ((threadIdx.x & 63) == 0) { red[wv * 2] = m0; red[wv * 2 + 1] = m1; }
        __syncthreads();
        if (threadIdx.x == 0) {
            float a0 = fminf(fminf(red[0], red[2]), fminf(red[4], red[6]));
            float a1 = fminf(fminf(red[1], red[3]), fminf(red[5], red[7]));
            blockmin[bid] = make_float2(a0, a1);
        }
    } else if (bid < 530) {
        // frag q = t*8 + ks*2 + nt; lane l: B[k=ks*16+(l>>5)*8+j][n=nt*32+(l&31)]
        int tid = (bid - 512) * 256 + threadIdx.x;
        if (tid >= 4608) return;
        int l  = tid & 63;
        int q  = tid >> 6;
        int nt = q & 1;
        int ks = (q >> 1) & 3;
        int t  = q >> 3;
        int n  = nt * 32 + (l & 31);
        int kb = ks * 16 + (l >> 5) * 8;
        half8v v;
        #pragma unroll
        for (int j = 0; j < 8; ++j)
            v[j] = (_Float16)W[(t * 64 + kb + j) * 64 + n];
        ((half8v*)bpk)[q * 64 + l] = v;
    } else {
        int tid = (bid - 530) * 256 + threadIdx.x;  // [0,524288)
        if (bid == 530 && threadIdx.x < 8) {        // zero row NPTS
            half8v z = {};
            *(half8v*)(fb + (long)NPTS * 64 + threadIdx.x * 8) = z;
        }
        #pragma unroll
        for (int r = 0; r < 4; ++r) {
            long i = tid + (long)r * 524288;        // 2,097,152 float4 total
            float4 f = ((const float4*)feats)[i];
            half4v o = {(_Float16)f.x, (_Float16)f.y, (_Float16)f.z, (_Float16)f.w};
            *(half4v*)(fb + i * 4) = o;
        }
    }
}

// ---- cell index + rulebook scatter (max id wins); min-fold at head --------
__global__ __launch_bounds__(256) void k_grid(const float* __restrict__ s0a,
                                              const float* __restrict__ s1a,
                                              const float2* __restrict__ blockmin,
                                              int* __restrict__ pidx,
                                              int* __restrict__ grid) {
    __shared__ float red[8];
    float2 ba = blockmin[threadIdx.x];
    float2 bb = blockmin[threadIdx.x + 256];
    float m0 = fminf(ba.x, bb.x), m1 = fminf(ba.y, bb.y);
    #pragma unroll
    for (int off = 32; off; off >>= 1) {
        m0 = fminf(m0, __shfl_down(m0, off));
        m1 = fminf(m1, __shfl_down(m1, off));
    }
    int wv = threadIdx.x >> 6;
    if ((threadIdx.x & 63) == 0) { red[wv * 2] = m0; red[wv * 2 + 1] = m1; }
    __syncthreads();
    m0 = fminf(fminf(red[0], red[2]), fminf(red[4], red[6]));
    m1 = fminf(fminf(red[1], red[3]), fminf(red[5], red[7]));

    int i = blockIdx.x * 256 + threadIdx.x;
    int iy = (int)((s0a[i] - m0) * 256.0f);
    int ix = (int)((s1a[i] - m1) * 256.0f);
    pidx[i] = (iy << 8) | ix;
    int b = i >> 15;
    atomicMax(&grid[(b << 16) + (iy << 8) + ix], i);
}

// ---- MFMA conv: coalesced A via global_load_lds + per-tap B in shared LDS --
// Wave = 32 points x 64 couts. Per tap: 4 A-loads (8 lanes cover one 128B row,
// source pre-swizzled u^g, LDS dest linear) + 2 B-loads (block-cooperative,
// 8KB/tap double-buffered). One __syncthreads per tap (its implicit vmcnt(0)
// drain = the pipeline wait); tap t+1 loads issued post-barrier fly under
// tap t's 16 MFMAs. Fragments bit-identical to R12 -> same output.
// A-frag: lane l holds A[row=l&31][k=ks*16+(l>>5)*8+j].
// C/D: col=lane&31, row=(reg&3)+8*(reg>>2)+4*(lane>>5)   [HW-verified]
__global__ __launch_bounds__(256, 3) void k_mconv(const _Float16* __restrict__ fb,
                                                  const _Float16* __restrict__ bpk,
                                                  const int* __restrict__ pidx,
                                                  const int* __restrict__ grid,
                                                  float* __restrict__ out) {
    __shared__ int      nidb[4][9][32];             // 4.5 KB
    __shared__ _Float16 ash[4][2][2048];            // 32 KB  (A: per-wave dbuf)
    __shared__ _Float16 bsh[2][4096];               // 16 KB  (B: per-tap dbuf)

    const int lane  = threadIdx.x & 63;
    const int wv    = threadIdx.x >> 6;
    const int pbase = (blockIdx.x << 7) + (wv << 5);
    const int prow  = lane & 31;
    const int khalf = lane >> 5;
    const int h     = prow & 7;

    // precompute all 9 neighbor ids for this wave's 32 points -> LDS
    if (lane < 32) {
        const int p  = pbase + lane;
        const int pk = pidx[p];
        const int iy = pk >> 8;
        const int ix = pk & 255;
        const int* gb = grid + ((p >> 15) << 16);
        #pragma unroll
        for (int t = 0; t < 9; ++t) {
            const int ny = iy + t / 3 - 1;
            const int nx = ix + t % 3 - 1;
            int n = ((unsigned)ny < 256u && (unsigned)nx < 256u) ? gb[(ny << 8) + nx] : -1;
            nidb[wv][t][lane] = (n < 0) ? NPTS : n;  // zero row for invalid taps
        }
    }
    __syncthreads();

    const int g = lane >> 3;                         // row group 0..7
    const int u = lane & 7;                          // 16B unit within row

    f32x16 acc0, acc1;
    #pragma unroll
    for (int r = 0; r < 16; ++r) { acc0[r] = 0.0f; acc1[r] = 0.0f; }

    // ---- staging issue helpers (source swizzled, LDS linear: rule #21) ----
    #define ISSUE_A(t, buf)                                                    \
        {                                                                      \
            _Pragma("unroll")                                                  \
            for (int m = 0; m < 4; ++m) {                                      \
                int r_ = nidb[wv][t][m * 8 + g];                               \
                const _Float16* src_ = fb + ((long)r_ << 6) + ((u ^ g) << 3);  \
                gl_lds16(src_, &ash[wv][buf][m * 512]);                        \
            }                                                                  \
        }
    #define ISSUE_B(t, buf)                                                    \
        {                                                                      \
            _Pragma("unroll")                                                  \
            for (int m = 0; m < 2; ++m) {                                      \
                int f_ = wv * 2 + m;                                           \
                const _Float16* src_ = bpk + (((t) * 512 + f_ * 64 + lane) << 3); \
                gl_lds16(src_, &bsh[buf][f_ * 512]);                           \
            }                                                                  \
        }

    ISSUE_A(0, 0)
    ISSUE_B(0, 0)

    #pragma unroll
    for (int t = 0; t < 9; ++t) {
        const int buf = t & 1;
        __syncthreads();                 // drains vmcnt(0): tap-t staged everywhere
        if (t < 8) {                     // issue t+1 into other buffer (safe: all
            ISSUE_A(t + 1, buf ^ 1)      //  waves finished MFMA(t-1) pre-barrier)
            ISSUE_B(t + 1, buf ^ 1)
        }
        // fragment reads (un-swizzle) — identical data to R12's layout
        const half8v* aw = (const half8v*)&ash[wv][buf][0];
        half8v a0 = aw[prow * 8 + ((0 + khalf) ^ h)];
        half8v a1 = aw[prow * 8 + ((2 + khalf) ^ h)];
        half8v a2 = aw[prow * 8 + ((4 + khalf) ^ h)];
        half8v a3 = aw[prow * 8 + ((6 + khalf) ^ h)];
        const half8v* bb = (const half8v*)&bsh[buf][0];
        acc0 = __builtin_amdgcn_mfma_f32_32x32x16_f16(a0, bb[0 * 64 + lane], acc0, 0, 0, 0);
        acc1 = __builtin_amdgcn_mfma_f32_32x32x16_f16(a0, bb[1 * 64 + lane], acc1, 0, 0, 0);
        acc0 = __builtin_amdgcn_mfma_f32_32x32x16_f16(a1, bb[2 * 64 + lane], acc0, 0, 0, 0);
        acc1 = __builtin_amdgcn_mfma_f32_32x32x16_f16(a1, bb[3 * 64 + lane], acc1, 0, 0, 0);
        acc0 = __builtin_amdgcn_mfma_f32_32x32x16_f16(a2, bb[4 * 64 + lane], acc0, 0, 0, 0);
        acc1 = __builtin_amdgcn_mfma_f32_32x32x16_f16(a2, bb[5 * 64 + lane], acc1, 0, 0, 0);
        acc0 = __builtin_amdgcn_mfma_f32_32x32x16_f16(a3, bb[6 * 64 + lane], acc0, 0, 0, 0);
        acc1 = __builtin_amdgcn_mfma_f32_32x32x16_f16(a3, bb[7 * 64 + lane], acc1, 0, 0, 0);
    }

    #pragma unroll
    for (int r = 0; r < 16; ++r) {
        int orow = pbase + (r & 3) + ((r >> 2) << 3) + (khalf << 2);
        out[(long)orow * 64 + prow]      = acc0[r];
        out[(long)orow * 64 + 32 + prow] = acc1[r];
    }
    #undef ISSUE_A
    #undef ISSUE_B
}

extern "C" void kernel_launch(void* const* d_in, const int* in_sizes, int n_in,
                              void* d_out, int out_size, void* d_ws, size_t ws_size,
                              hipStream_t stream) {
    const float* inst   = (const float*)d_in[0]; // (B,G,64)
    const float* anchor = (const float*)d_in[1]; // (B,G,2)
    const float* W      = (const float*)d_in[2]; // (3,3,64,64)
    float* out = (float*)d_out;

    char* ws = (char*)d_ws;
    float*     s0a  = (float*)(ws);                      // 512 KB
    float*     s1a  = (float*)(ws + 524288);             // 512 KB
    int*       pidx = (int*)(ws + 1048576);              // 512 KB
    int*       grd  = (int*)(ws + 1572864);              // 1 MB
    float2*    bmin = (float2*)(ws + 2621440);           // 4 KB (512 float2)
    _Float16*  fb   = (_Float16*)(ws + 2625536);         // (N+1)*64 f16
    _Float16*  bpk  = (_Float16*)(ws + 19402880);        // 72 KB

    k_front<<<2578, 256, 0, stream>>>(anchor, W, inst, s0a, s1a, bmin, bpk, fb, grd);
    k_grid <<<512,  256, 0, stream>>>(s0a, s1a, bmin, pidx, grd);
    k_mconv<<<1024, 256, 0, stream>>>(fb, bpk, pidx, grd, out);
}